// Round 11
// baseline (124.640 us; speedup 1.0000x reference)
//
#include <hip/hip_runtime.h>
#include <hip/hip_bf16.h>

typedef int   i32x4 __attribute__((ext_vector_type(4)));
typedef float f32x4 __attribute__((ext_vector_type(4)));

#define NROWS 8192
#define KDIM  1024
#define BM 128
#define BN 128
#define BKB 128                        // K-bytes per step (128 i8)
#define NKT (KDIM / BKB)               // 8 K-steps
#define NTILE (NROWS / BM)             // 64 tile-rows
#define NBLK (NTILE * (NTILE + 1) / 2) // 2080 upper-tri blocks
#define QSCALE 16.0f                   // q = round(x * 16); s = 1/16
#define DEQ 0.0625f                    // 1/16

__device__ __forceinline__ void gl_lds16(const void* g, void* l) {
    __builtin_amdgcn_global_load_lds(
        (const __attribute__((address_space(1))) void*)g,
        (__attribute__((address_space(3))) void*)l, 16, 0, 0);
}

// One block per row: quantize to i8 (q = rn(x*16), |x|max ~5.65 -> no clip in
// practice) and compute exact integer sum of squares of the SAME quantized
// values -> d2 = sqi + sqj - 2*gram is exact (= sum (qa-qb)^2 >= 0; diag = 0).
// Input is read-once 32 MB -> nontemporal loads (don't pollute L2/L3; A8 must
// stay resident for the GEMM). NOTE: builtin needs ext_vector_type, not
// HIP_vector_type (R10 compile fix).
__global__ __launch_bounds__(256)
void prep_kernel(const float* __restrict__ in, signed char* __restrict__ a8,
                 int* __restrict__ sq) {
    const int row = blockIdx.x;
    const int t = threadIdx.x;
    const f32x4 v = __builtin_nontemporal_load(
        reinterpret_cast<const f32x4*>(in + (size_t)row * KDIM) + t);
    int q0 = __float2int_rn(v.x * QSCALE);
    int q1 = __float2int_rn(v.y * QSCALE);
    int q2 = __float2int_rn(v.z * QSCALE);
    int q3 = __float2int_rn(v.w * QSCALE);
    q0 = max(-127, min(127, q0));
    q1 = max(-127, min(127, q1));
    q2 = max(-127, min(127, q2));
    q3 = max(-127, min(127, q3));
    char4 c;
    c.x = (signed char)q0; c.y = (signed char)q1;
    c.z = (signed char)q2; c.w = (signed char)q3;
    reinterpret_cast<char4*>(a8 + (size_t)row * KDIM)[t] = c;
    int s = q0 * q0 + q1 * q1 + q2 * q2 + q3 * q3;
    #pragma unroll
    for (int off = 32; off > 0; off >>= 1) s += __shfl_down(s, off);
    __shared__ int red[4];
    if ((t & 63) == 0) red[t >> 6] = s;
    __syncthreads();
    if (t == 0) sq[row] = red[0] + red[1] + red[2] + red[3];
}

// C = A*A^T upper-tri tiles via mfma_i32_16x16x64_i8 (R8's proven WIN kernel).
// R1 skeleton: 128x128 tile, 4 waves (2x2 of 64x64), single-buffered LDS,
// 2 __syncthreads per K-step, BKB=128 -> 8 K-steps. Row-internal XOR swizzle
// (R7-verified): contiguous staging + conflict-free ds_read_b128.
// R9 delta: output stores are NONTEMPORAL (write-once 268 MB stream must not
// evict the L3-resident A8 panels -> cuts HBM re-fetch).
// Epilogue: d2 = sqi + sqj - 2*acc in EXACT int; out = -(1/16)*sqrt(d2).
// Off-diag tiles mirror-written (reg idx r contiguous in transposed addr).
__global__ __launch_bounds__(256)
void gemm_kernel(const signed char* __restrict__ A8, const int* __restrict__ sq,
                 float* __restrict__ out) {
    __shared__ __attribute__((aligned(16))) signed char As[BM][BKB]; // 16 KB
    __shared__ __attribute__((aligned(16))) signed char Bs[BN][BKB]; // 16 KB

    // XCD-aware swizzle: 2080 blocks, 2080 % 8 == 0 -> bijective
    const int bid = blockIdx.x;
    const int cpx = NBLK >> 3;  // 260
    const int swz = (bid & 7) * cpx + (bid >> 3);

    // triangular decode: swz -> (bi, bj), bi <= bj; tiles in rows < r: r*(129-r)/2
    int bi = (int)((129.0f - sqrtf(129.0f * 129.0f - 8.0f * (float)swz)) * 0.5f);
    if (bi > NTILE - 1) bi = NTILE - 1;
    if (bi < 0) bi = 0;
    while ((bi + 1) * (129 - (bi + 1)) / 2 <= swz) ++bi;
    while (bi * (129 - bi) / 2 > swz) --bi;
    const int bj = bi + (swz - bi * (129 - bi) / 2);

    const int brow = bi * BM;
    const int bcol = bj * BN;

    const int t = threadIdx.x;
    const int lane = t & 63;
    const int w = t >> 6;      // 0..3
    const int wr = w >> 1;     // 0..1
    const int wc = w & 1;      // 0..1
    const int l15 = lane & 15, l4 = lane >> 4;

    // ---- staging: issue i covers rows i*32..+31; 16B chunk per thread ----
    const int srow = t >> 3;                          // 0..31
    const int schunk = ((t & 7) ^ (srow & 7)) * 16;   // byte offset in row
    const signed char* gA[4];
    const signed char* gB[4];
    #pragma unroll
    for (int i = 0; i < 4; ++i) {
        gA[i] = A8 + (size_t)(brow + i * 32 + srow) * KDIM + schunk;
        gB[i] = A8 + (size_t)(bcol + i * 32 + srow) * KDIM + schunk;
    }

#define STAGE(kt) do { \
    _Pragma("unroll") for (int i_ = 0; i_ < 4; ++i_) \
        gl_lds16(gA[i_] + (kt) * BKB, (signed char*)&As[0][0] + i_ * 4096 + t * 16); \
    _Pragma("unroll") for (int i_ = 0; i_ < 4; ++i_) \
        gl_lds16(gB[i_] + (kt) * BKB, (signed char*)&Bs[0][0] + i_ * 4096 + t * 16); \
} while (0)

    // ---- fragment read offsets (bytes) ----
    const int cx = l15 & 7;
    const int aRow = (wr * 64 + l15) * BKB;
    const int bRow = (wc * 64 + l15) * BKB;
    const int off0 = ((l4) ^ cx) * 16;       // kk = 0
    const int off1 = ((4 + l4) ^ cx) * 16;   // kk = 1

    i32x4 acc[4][4] = {};

    for (int kt = 0; kt < NKT; ++kt) {
        STAGE(kt);
        __syncthreads();

        i32x4 af[4][2], bf[4][2];
        #pragma unroll
        for (int m = 0; m < 4; ++m) {
            af[m][0] = *reinterpret_cast<const i32x4*>(&As[0][0] + aRow + m * 2048 + off0);
            af[m][1] = *reinterpret_cast<const i32x4*>(&As[0][0] + aRow + m * 2048 + off1);
        }
        #pragma unroll
        for (int n = 0; n < 4; ++n) {
            bf[n][0] = *reinterpret_cast<const i32x4*>(&Bs[0][0] + bRow + n * 2048 + off0);
            bf[n][1] = *reinterpret_cast<const i32x4*>(&Bs[0][0] + bRow + n * 2048 + off1);
        }

        #pragma unroll
        for (int m = 0; m < 4; ++m)
            #pragma unroll
            for (int n = 0; n < 4; ++n) {
                acc[m][n] = __builtin_amdgcn_mfma_i32_16x16x64_i8(af[m][0], bf[n][0], acc[m][n], 0, 0, 0);
                acc[m][n] = __builtin_amdgcn_mfma_i32_16x16x64_i8(af[m][1], bf[n][1], acc[m][n], 0, 0, 0);
            }
        __syncthreads();
    }

    // ---- epilogue: C/D layout col = lane&15, row = (lane>>4)*4 + reg ----
    const int ib = brow + wr * 64 + l4 * 4;
    const int jb = bcol + wc * 64 + l15;
    int sqj[4];
    #pragma unroll
    for (int n = 0; n < 4; ++n) sqj[n] = sq[jb + n * 16];

    const bool offdiag = (bi != bj);
    #pragma unroll
    for (int m = 0; m < 4; ++m) {
        int sqi[4];
        #pragma unroll
        for (int r = 0; r < 4; ++r) sqi[r] = sq[ib + m * 16 + r];
        #pragma unroll
        for (int n = 0; n < 4; ++n) {
            float tv[4];
            #pragma unroll
            for (int r = 0; r < 4; ++r) {
                const int d2 = sqi[r] + sqj[n] - 2 * acc[m][n][r];  // exact, >= 0
                tv[r] = -DEQ * sqrtf(fmaxf((float)d2, 0.0f));
            }
            #pragma unroll
            for (int r = 0; r < 4; ++r)
                __builtin_nontemporal_store(
                    tv[r], &out[(size_t)(ib + m * 16 + r) * NROWS + (jb + n * 16)]);
            if (offdiag) {
                const size_t mrow = (size_t)(jb + n * 16) * NROWS + (ib + m * 16);
                __builtin_nontemporal_store(
                    *reinterpret_cast<f32x4*>(tv),
                    reinterpret_cast<f32x4*>(&out[mrow]));
            }
        }
    }
#undef STAGE
}

extern "C" void kernel_launch(void* const* d_in, const int* in_sizes, int n_in,
                              void* d_out, int out_size, void* d_ws, size_t ws_size,
                              hipStream_t stream) {
    const float* feat = (const float*)d_in[0];
    float* out = (float*)d_out;
    signed char* a8 = (signed char*)d_ws;                          // 8 MB i8 copy
    int* sq = (int*)((char*)d_ws + (size_t)NROWS * KDIM);          // 32 KB row sums (int)

    prep_kernel<<<NROWS, 256, 0, stream>>>(feat, a8, sq);
    gemm_kernel<<<NBLK, 256, 0, stream>>>(a8, sq, out);
}

// Round 12
// 106.768 us; speedup vs baseline: 1.1674x; 1.1674x over previous
//
#include <hip/hip_runtime.h>
#include <hip/hip_bf16.h>

typedef int   i32x4 __attribute__((ext_vector_type(4)));
typedef float f32x4 __attribute__((ext_vector_type(4)));

#define NROWS 8192
#define KDIM  1024
#define BM 128
#define BN 128
#define BKB 128                        // K-bytes per step (128 i8)
#define NKT (KDIM / BKB)               // 8 K-steps
#define NTILE (NROWS / BM)             // 64 tile-rows
#define NBLK (NTILE * (NTILE + 1) / 2) // 2080 upper-tri blocks
#define QSCALE 16.0f                   // q = round(x * 16); s = 1/16
#define DEQ 0.0625f                    // 1/16

__device__ __forceinline__ void gl_lds16(const void* g, void* l) {
    __builtin_amdgcn_global_load_lds(
        (const __attribute__((address_space(1))) void*)g,
        (__attribute__((address_space(3))) void*)l, 16, 0, 0);
}

// One block per row: quantize to i8 (q = rn(x*16)) and exact integer row
// sum-of-squares of the SAME quantized values -> d2 exact, diag = 0. (R8 form;
// R11's nontemporal experiments reverted -- measured regression.)
__global__ __launch_bounds__(256)
void prep_kernel(const float* __restrict__ in, signed char* __restrict__ a8,
                 int* __restrict__ sq) {
    const int row = blockIdx.x;
    const int t = threadIdx.x;
    const float4 v = reinterpret_cast<const float4*>(in + (size_t)row * KDIM)[t];
    int q0 = __float2int_rn(v.x * QSCALE);
    int q1 = __float2int_rn(v.y * QSCALE);
    int q2 = __float2int_rn(v.z * QSCALE);
    int q3 = __float2int_rn(v.w * QSCALE);
    q0 = max(-127, min(127, q0));
    q1 = max(-127, min(127, q1));
    q2 = max(-127, min(127, q2));
    q3 = max(-127, min(127, q3));
    char4 c;
    c.x = (signed char)q0; c.y = (signed char)q1;
    c.z = (signed char)q2; c.w = (signed char)q3;
    reinterpret_cast<char4*>(a8 + (size_t)row * KDIM)[t] = c;
    int s = q0 * q0 + q1 * q1 + q2 * q2 + q3 * q3;
    #pragma unroll
    for (int off = 32; off > 0; off >>= 1) s += __shfl_down(s, off);
    __shared__ int red[4];
    if ((t & 63) == 0) red[t >> 6] = s;
    __syncthreads();
    if (t == 0) sq[row] = red[0] + red[1] + red[2] + red[3];
}

// C = A*A^T upper-tri tiles via mfma_i32_16x16x64_i8 (R8's WIN kernel,
// 103.6 us). R12 delta: LDS-TRANSPOSE EPILOGUE -- after the K-loop each wave
// reuses its private 8 KB of the staging LDS to transpose its 64x64 sub-tile
// (two 32-row halves), so the direct writes become float4 stores in 256 B
// contiguous runs (full L2 lines: no write-allocate fetch, 4x fewer store
// instrs). Mirror path (already float4) and all arithmetic unchanged.
__global__ __launch_bounds__(256)
void gemm_kernel(const signed char* __restrict__ A8, const int* __restrict__ sq,
                 float* __restrict__ out) {
    __shared__ __attribute__((aligned(16))) char smem[32768];
    signed char* Asb = (signed char*)smem;            // 16 KB A panel
    signed char* Bsb = (signed char*)smem + 16384;    // 16 KB B panel

    // XCD-aware swizzle: 2080 blocks, 2080 % 8 == 0 -> bijective
    const int bid = blockIdx.x;
    const int cpx = NBLK >> 3;  // 260
    const int swz = (bid & 7) * cpx + (bid >> 3);

    // triangular decode: swz -> (bi, bj), bi <= bj; tiles in rows < r: r*(129-r)/2
    int bi = (int)((129.0f - sqrtf(129.0f * 129.0f - 8.0f * (float)swz)) * 0.5f);
    if (bi > NTILE - 1) bi = NTILE - 1;
    if (bi < 0) bi = 0;
    while ((bi + 1) * (129 - (bi + 1)) / 2 <= swz) ++bi;
    while (bi * (129 - bi) / 2 > swz) --bi;
    const int bj = bi + (swz - bi * (129 - bi) / 2);

    const int brow = bi * BM;
    const int bcol = bj * BN;

    const int t = threadIdx.x;
    const int lane = t & 63;
    const int w = t >> 6;      // 0..3
    const int wr = w >> 1;     // 0..1
    const int wc = w & 1;      // 0..1
    const int l15 = lane & 15, l4 = lane >> 4;

    // ---- staging: issue i covers rows i*32..+31; 16B chunk per thread ----
    const int srow = t >> 3;                          // 0..31
    const int schunk = ((t & 7) ^ (srow & 7)) * 16;   // byte offset in row
    const signed char* gA[4];
    const signed char* gB[4];
    #pragma unroll
    for (int i = 0; i < 4; ++i) {
        gA[i] = A8 + (size_t)(brow + i * 32 + srow) * KDIM + schunk;
        gB[i] = A8 + (size_t)(bcol + i * 32 + srow) * KDIM + schunk;
    }

#define STAGE(kt) do { \
    _Pragma("unroll") for (int i_ = 0; i_ < 4; ++i_) \
        gl_lds16(gA[i_] + (kt) * BKB, Asb + i_ * 4096 + t * 16); \
    _Pragma("unroll") for (int i_ = 0; i_ < 4; ++i_) \
        gl_lds16(gB[i_] + (kt) * BKB, Bsb + i_ * 4096 + t * 16); \
} while (0)

    // ---- fragment read offsets (bytes) ----
    const int cx = l15 & 7;
    const int aRow = (wr * 64 + l15) * BKB;
    const int bRow = (wc * 64 + l15) * BKB;
    const int off0 = ((l4) ^ cx) * 16;       // kk = 0
    const int off1 = ((4 + l4) ^ cx) * 16;   // kk = 1

    i32x4 acc[4][4] = {};

    for (int kt = 0; kt < NKT; ++kt) {
        STAGE(kt);
        __syncthreads();

        i32x4 af[4][2], bf[4][2];
        #pragma unroll
        for (int m = 0; m < 4; ++m) {
            af[m][0] = *reinterpret_cast<const i32x4*>(Asb + aRow + m * 2048 + off0);
            af[m][1] = *reinterpret_cast<const i32x4*>(Asb + aRow + m * 2048 + off1);
        }
        #pragma unroll
        for (int n = 0; n < 4; ++n) {
            bf[n][0] = *reinterpret_cast<const i32x4*>(Bsb + bRow + n * 2048 + off0);
            bf[n][1] = *reinterpret_cast<const i32x4*>(Bsb + bRow + n * 2048 + off1);
        }

        #pragma unroll
        for (int m = 0; m < 4; ++m)
            #pragma unroll
            for (int n = 0; n < 4; ++n) {
                acc[m][n] = __builtin_amdgcn_mfma_i32_16x16x64_i8(af[m][0], bf[n][0], acc[m][n], 0, 0, 0);
                acc[m][n] = __builtin_amdgcn_mfma_i32_16x16x64_i8(af[m][1], bf[n][1], acc[m][n], 0, 0, 0);
            }
        __syncthreads();   // after last iter: staging LDS free -> epilogue reuse
    }

    // ---- epilogue ----
    // C/D layout: col = lane&15 (l15), row = l4*4 + reg [verified R1-R8].
    // Wave sub-tile: rows brow+wr*64+(0..63), cols bcol+wc*64+(0..63).
    // Per-wave private 8 KB: lw[32][64] floats; two halves h (m = 2h,2h+1).
    float* lw = (float*)(smem + w * 8192);
    const int ib = brow + wr * 64 + l4 * 4;
    const int jb = bcol + wc * 64 + l15;
    int sqj[4];
    #pragma unroll
    for (int n = 0; n < 4; ++n) sqj[n] = sq[jb + n * 16];

    const bool offdiag = (bi != bj);
    #pragma unroll
    for (int h = 0; h < 2; ++h) {
        // scatter final values into lw (transposed-by-read layout)
        #pragma unroll
        for (int mm = 0; mm < 2; ++mm) {
            const int m = 2 * h + mm;
            int sqi[4];
            #pragma unroll
            for (int r = 0; r < 4; ++r) sqi[r] = sq[ib + m * 16 + r];
            #pragma unroll
            for (int n = 0; n < 4; ++n) {
                float tv[4];
                #pragma unroll
                for (int r = 0; r < 4; ++r) {
                    const int d2 = sqi[r] + sqj[n] - 2 * acc[m][n][r];  // exact, >= 0
                    tv[r] = -DEQ * sqrtf(fmaxf((float)d2, 0.0f));
                    lw[(mm * 16 + l4 * 4 + r) * 64 + n * 16 + l15] = tv[r];
                }
                if (offdiag) {
                    const size_t mrow = (size_t)(jb + n * 16) * NROWS + (ib + m * 16);
                    *reinterpret_cast<f32x4*>(&out[mrow]) = *reinterpret_cast<f32x4*>(tv);
                }
            }
        }
        // wave-local: all lanes' ds_writes complete before cross-lane reads
        asm volatile("s_waitcnt lgkmcnt(0)" ::: "memory");
        // read back row-major and store 256B-contiguous float4 runs
        #pragma unroll
        for (int rg = 0; rg < 8; ++rg) {
            const int rr = rg * 4 + l4;   // 0..31
            const f32x4 v = *reinterpret_cast<const f32x4*>(&lw[rr * 64 + l15 * 4]);
            const size_t drow =
                (size_t)(brow + wr * 64 + h * 32 + rr) * NROWS + (bcol + wc * 64 + l15 * 4);
            *reinterpret_cast<f32x4*>(&out[drow]) = v;
        }
        // next half's ds_writes follow this half's ds_reads in wave-order (LDS
        // ops execute in issue order within a wave) -> no extra wait needed
    }
#undef STAGE
}

extern "C" void kernel_launch(void* const* d_in, const int* in_sizes, int n_in,
                              void* d_out, int out_size, void* d_ws, size_t ws_size,
                              hipStream_t stream) {
    const float* feat = (const float*)d_in[0];
    float* out = (float*)d_out;
    signed char* a8 = (signed char*)d_ws;                          // 8 MB i8 copy
    int* sq = (int*)((char*)d_ws + (size_t)NROWS * KDIM);          // 32 KB row sums (int)

    prep_kernel<<<NROWS, 256, 0, stream>>>(feat, a8, sq);
    gemm_kernel<<<NBLK, 256, 0, stream>>>(a8, sq, out);
}